// Round 4
// baseline (126.586 us; speedup 1.0000x reference)
//
#include <hip/hip_runtime.h>
#include <math.h>

#define OUTSZ   224
#define NBINS   8
#define NTH     256
#define IMG_H   512
#define IMG_W   512
#define HW      (IMG_H * IMG_W)   // 262144
#define CHUNKS  4
#define RPC     (OUTSZ / CHUNKS)  // 56 rows per chunk

// ---------------- pre-pass: (N,2,H,W) -> (N,H,W,2) ----------------
__global__ __launch_bounds__(NTH) void interleave_kernel(
    const float* __restrict__ flows, float2* __restrict__ inter)
{
    const int g   = blockIdx.x * NTH + threadIdx.x;  // one group = 4 pixels
    const int n   = g >> 16;                         // HW/4 = 65536 groups/plane
    const int hw4 = (g & 0xFFFF) << 2;
    const float4 a = *(const float4*)(flows + (size_t)(2 * n) * HW + hw4);
    const float4 b = *(const float4*)(flows + (size_t)(2 * n + 1) * HW + hw4);
    float4* o = (float4*)(inter + (size_t)n * HW + hw4);
    o[0] = make_float4(a.x, b.x, a.y, b.y);
    o[1] = make_float4(a.z, b.z, a.w, b.w);
}

// ---------------- main kernel: register histogram ----------------
__global__ __launch_bounds__(NTH) void velhist_fast(
    const void* __restrict__ src,      // (N,H,W,2) interleaved
    const float* __restrict__ boxes,   // (M,5)
    float* __restrict__ ws)            // partials: [M*CHUNKS][16]
{
    const int bid   = blockIdx.x;
    const int m     = bid >> 2;
    const int chunk = bid & 3;
    const int tid   = threadIdx.x;

    __shared__ float4 s_row[RPC];         // per-row y state
    __shared__ float2 s_h[NBINS * NTH];   // 16 KB reduce buffer

    const float bxf = boxes[m * 5 + 0];
    const float x1  = boxes[m * 5 + 1];
    const float y1  = boxes[m * 5 + 2];
    const float x2  = boxes[m * 5 + 3];
    const float y2  = boxes[m * 5 + 4];
    const int  bidx = (int)bxf;
    const float roi_w = fmaxf(x2 - x1, 1.0f);
    const float roi_h = fmaxf(y2 - y1, 1.0f);
    const float GINV  = 1.0f / (float)OUTSZ;

    // per-row y-state: {wy0, wy1 (sign bit = !vy), r0_byteoff, r1_byteoff}
    if (tid < RPC) {
        const int row   = chunk * RPC + tid;
        const float gy  = ((float)row + 0.5f) * GINV;
        const float py  = y1 + gy * roi_h;
        const bool  vy  = (py >= -1.0f) && (py <= (float)IMG_H);
        const float pcy = fminf(fmaxf(py, 0.0f), (float)(IMG_H - 1));
        const int   y0  = (int)pcy;
        const float fy  = pcy - (float)y0;
        const int   y1r = min(y0 + 1, IMG_H - 1);
        const float wy0 = vy ? (1.0f - fy) : 0.0f;
        const float wy1 = vy ? fy : -0.0f;           // sign bit encodes !vy
        s_row[tid] = make_float4(wy0, wy1,
                                 __int_as_float(y0  << 12),   // *4096 B/row
                                 __int_as_float(y1r << 12));
    }

    // lane -> (column, row-range) mapping: waves 0-2 take cols 0..191 x 56 rows,
    // wave 3 splits cols 192..223 across two 28-row halves (no idle lanes)
    int col, tbloff, nrows;
    if (tid < 192) { col = tid;              tbloff = 0;                     nrows = RPC;     }
    else           { col = 192 + (tid & 31); tbloff = (tid & 32) ? RPC/2 : 0; nrows = RPC/2; }

    // per-column x state
    float wx0, wx1;
    int   x0b, vxi;
    {
        const float gx  = ((float)col + 0.5f) * GINV;
        const float px  = x1 + gx * roi_w;
        const bool  vx  = (px >= -1.0f) && (px <= (float)IMG_W);
        const float pcx = fminf(fmaxf(px, 0.0f), (float)(IMG_W - 1));
        const int   x0  = (int)pcx;
        const float fx  = pcx - (float)x0;
        const float vxf = vx ? 1.0f : 0.0f;
        x0b = x0 << 3;             // float2 pixel = 8 B
        wx0 = (1.0f - fx) * vxf;   // vx folded into weights -> a=b=0 when !vx
        wx1 = fx * vxf;
        vxi = vx ? 1 : 0;
    }

    const char* base = (const char*)src + (size_t)bidx * HW * sizeof(float2);

    float accs[NBINS];
    int   accc[NBINS];
#pragma unroll
    for (int b = 0; b < NBINS; ++b) { accs[b] = 0.0f; accc[b] = 0; }

    __syncthreads();

#pragma unroll 4
    for (int r = 0; r < nrows; ++r) {
        const float4 rs = s_row[tbloff + r];
        const int r0b = __float_as_int(rs.z);
        const int r1b = __float_as_int(rs.w);

        // one dwordx4 covers pixels x0 and x0+1, both channels
        const float4 p0 = *(const float4*)(base + (r0b + x0b));
        const float4 p1 = *(const float4*)(base + (r1b + x0b));

        const float w00 = rs.x * wx0, w01 = rs.x * wx1;
        const float w10 = rs.y * wx0, w11 = rs.y * wx1;
        const float a = p0.x * w00 + p0.z * w01 + p1.x * w10 + p1.z * w11;
        const float b = p0.y * w00 + p0.w * w01 + p1.y * w10 + p1.w * w11;

        const float mag = __builtin_amdgcn_sqrtf(a * a + b * b);

        // octant of atan2(a,b) from sign/magnitude bits, Gray-decoded
        const int ia = __float_as_int(a), ib = __float_as_int(b);
        const int sa = (int)((unsigned)ia >> 31);
        const int sb = (int)((unsigned)ib >> 31);
        const int u  = sa ^ sb;
        const int aa = ia & 0x7fffffff, ab = ib & 0x7fffffff;
        const int t  = (aa >= ab) ? 1 : 0;
        int bin = ((sa ^ 1) << 2) | (u << 1) | (u ^ t);
        const int bad = (vxi ^ 1) | (int)((unsigned)__float_as_int(rs.y) >> 31);
        bin = bad ? 4 : bin;     // invalid: mag=0, atan2(0,0)=0 -> bin 4

        // register histogram: 8 predicated accumulate chains, no LDS RMW
#pragma unroll
        for (int bb = 0; bb < NBINS; ++bb) {
            const bool sel = (bin == bb);
            accs[bb] += sel ? mag : 0.0f;
            accc[bb] += sel ? 1 : 0;
        }
    }

    // dump to LDS and tree-reduce 256 -> 1 per bin
#pragma unroll
    for (int b = 0; b < NBINS; ++b)
        s_h[(b << 8) + tid] = make_float2(accs[b], (float)accc[b]);

    int sh = 7;
    for (int off = 128; off >= 1; off >>= 1, --sh) {
        __syncthreads();
        for (int w = tid; w < NBINS * off; w += NTH) {
            const int b  = w >> sh;
            const int t2 = w & (off - 1);
            float2 lo = s_h[(b << 8) + t2];
            float2 hi = s_h[(b << 8) + t2 + off];
            lo.x += hi.x; lo.y += hi.y;
            s_h[(b << 8) + t2] = lo;
        }
    }
    __syncthreads();

    if (tid < NBINS) {
        const float2 h = s_h[tid << 8];
        float* pp = ws + bid * 16;
        pp[tid]     = h.x;
        pp[tid + 8] = h.y;
    }
}

// ---------------- fallback: planar, LDS histogram (R3 path) ----------------
template <int CH>
__global__ __launch_bounds__(NTH) void velhist_planar(
    const float* __restrict__ flows,
    const float* __restrict__ boxes,
    float* __restrict__ ws,            // partials if CH>1
    float* __restrict__ out)           // (M,8) if CH==1
{
    constexpr int RP = OUTSZ / CH;
    const int bid   = blockIdx.x;
    const int m     = (CH == 1) ? bid : (bid / CH);
    const int chunk = (CH == 1) ? 0   : (bid - m * CH);
    const int tid   = threadIdx.x;

    __shared__ float2 s_h[NBINS * NTH];

#pragma unroll
    for (int b = 0; b < NBINS; ++b)
        s_h[(b << 8) + tid] = make_float2(0.0f, 0.0f);

    const float bxf = boxes[m * 5 + 0];
    const float x1  = boxes[m * 5 + 1];
    const float y1  = boxes[m * 5 + 2];
    const float x2  = boxes[m * 5 + 3];
    const float y2  = boxes[m * 5 + 4];
    const int  bidx = (int)bxf;
    const float roi_w = fmaxf(x2 - x1, 1.0f);
    const float roi_h = fmaxf(y2 - y1, 1.0f);
    const float GINV  = 1.0f / (float)OUTSZ;

    const float* __restrict__ f0 = flows + (size_t)bidx * 2 * HW;
    const float* __restrict__ f1 = f0 + HW;

    __syncthreads();

    if (tid < OUTSZ) {
        const float gx  = ((float)tid + 0.5f) * GINV;
        const float px  = x1 + gx * roi_w;
        const bool  vx  = (px >= -1.0f) && (px <= (float)IMG_W);
        const float pcx = fminf(fmaxf(px, 0.0f), (float)(IMG_W - 1));
        const int   x0  = (int)pcx;
        const float fx  = pcx - (float)x0;
        const int   x1i = min(x0 + 1, IMG_W - 1);
        const float vxf = vx ? 1.0f : 0.0f;
        const float wx0 = (1.0f - fx) * vxf;
        const float wx1 = fx * vxf;

        for (int r = 0; r < RP; ++r) {
            const int row   = chunk * RP + r;
            const float gy  = ((float)row + 0.5f) * GINV;
            const float py  = y1 + gy * roi_h;
            const bool  vy  = (py >= -1.0f) && (py <= (float)IMG_H);
            const float pcy = fminf(fmaxf(py, 0.0f), (float)(IMG_H - 1));
            const int   y0  = (int)pcy;
            const float fy  = pcy - (float)y0;
            const int   y1r = min(y0 + 1, IMG_H - 1);
            const float wy0 = vy ? (1.0f - fy) : 0.0f;
            const float wy1 = vy ? fy : 0.0f;

            const int r0 = y0 << 9, r1 = y1r << 9;
            const float w00 = wy0 * wx0, w01 = wy0 * wx1;
            const float w10 = wy1 * wx0, w11 = wy1 * wx1;

            const float a = f0[r0+x0]*w00 + f0[r0+x1i]*w01 + f0[r1+x0]*w10 + f0[r1+x1i]*w11;
            const float b = f1[r0+x0]*w00 + f1[r0+x1i]*w01 + f1[r1+x0]*w10 + f1[r1+x1i]*w11;

            const float mag = __builtin_amdgcn_sqrtf(a * a + b * b);

            const int p = (a >= 0.0f);
            const int q = (b >= 0.0f);
            const int t = (fabsf(a) >= fabsf(b));
            const int u = p ^ q;
            int bin = (p << 2) | (u << 1) | (u ^ t);
            if (!(vx && vy)) bin = 4;

            float2 h = s_h[(bin << 8) + tid];
            h.x += mag; h.y += 1.0f;
            s_h[(bin << 8) + tid] = h;
        }
    }

    int sh = 7;
    for (int off = 128; off >= 1; off >>= 1, --sh) {
        __syncthreads();
        for (int w = tid; w < NBINS * off; w += NTH) {
            const int b  = w >> sh;
            const int t2 = w & (off - 1);
            float2 lo = s_h[(b << 8) + t2];
            float2 hi = s_h[(b << 8) + t2 + off];
            lo.x += hi.x; lo.y += hi.y;
            s_h[(b << 8) + t2] = lo;
        }
    }
    __syncthreads();

    if (tid < NBINS) {
        const float2 h = s_h[tid << 8];
        if (CH == 1) {
            out[m * NBINS + tid] = (h.y != 0.0f) ? (h.x / fmaxf(h.y, 1.0f)) : 0.0f;
        } else {
            float* pp = ws + bid * 16;
            pp[tid]     = h.x;
            pp[tid + 8] = h.y;
        }
    }
}

__global__ __launch_bounds__(NTH) void finalize_kernel(
    const float* __restrict__ ws, float* __restrict__ out, int M, int chunks)
{
    const int i = blockIdx.x * NTH + threadIdx.x;
    if (i >= M * NBINS) return;
    const int m = i >> 3;
    const int b = i & 7;
    float s = 0.0f, c = 0.0f;
    for (int ch = 0; ch < chunks; ++ch) {
        const float* p = ws + (size_t)(m * chunks + ch) * 16;
        s += p[b];
        c += p[b + 8];
    }
    out[i] = (c != 0.0f) ? (s / fmaxf(c, 1.0f)) : 0.0f;
}

extern "C" void kernel_launch(void* const* d_in, const int* in_sizes, int n_in,
                              void* d_out, int out_size, void* d_ws, size_t ws_size,
                              hipStream_t stream) {
    const float* flows = (const float*)d_in[0];
    const float* boxes = (const float*)d_in[1];
    float* out = (float*)d_out;
    const int M = in_sizes[1] / 5;            // 512
    const int N = in_sizes[0] / (2 * HW);     // 8

    const size_t interBytes = (size_t)N * HW * sizeof(float2) + 16;  // +16 B pad for corner over-read
    const size_t partBytes  = (size_t)M * CHUNKS * 16 * sizeof(float);

    if (ws_size >= interBytes + partBytes) {
        float2* inter = (float2*)d_ws;
        float*  part  = (float*)((char*)d_ws + interBytes);
        interleave_kernel<<<dim3((N * HW / 4) / NTH), dim3(NTH), 0, stream>>>(flows, inter);
        velhist_fast<<<dim3(M * CHUNKS), dim3(NTH), 0, stream>>>(
            (const void*)inter, boxes, part);
        finalize_kernel<<<dim3((M * NBINS + NTH - 1) / NTH), dim3(NTH), 0, stream>>>(
            part, out, M, CHUNKS);
    } else if (ws_size >= partBytes) {
        velhist_planar<CHUNKS><<<dim3(M * CHUNKS), dim3(NTH), 0, stream>>>(
            flows, boxes, (float*)d_ws, nullptr);
        finalize_kernel<<<dim3((M * NBINS + NTH - 1) / NTH), dim3(NTH), 0, stream>>>(
            (const float*)d_ws, out, M, CHUNKS);
    } else {
        velhist_planar<1><<<dim3(M), dim3(NTH), 0, stream>>>(
            flows, boxes, nullptr, out);
    }
}